// Round 7
// baseline (2127.669 us; speedup 1.0000x reference)
//
#include <hip/hip_runtime.h>
#include <hip/hip_bf16.h>

// LSTM: S=512, B=128, I=256, H=512. Gates stacked (f,i,o,c) along dim0 of W/U.
// FP32 tensors; MFMA in bf16; epilogue/state fp32.
//
// Persistent cooperative kernel, 256 WGs x 256 thr:
//   - 4 independent batch-groups x 32 rows; 64 WGs/group (8 H-cols each).
//   - Wave split (mq,nq) = (row-half, K-half); LDS partial planes (parity dbuf).
//   - TAGGED h-exchange: u32 cell = (epoch<<16)|bf16(h) via IF$ (sc0 sc1).
//     Producer: single fire-and-forget store (no ack, no flag).
//     Consumer: speculative fragment load + tag validation (poll == load).
//   - One __syncthreads per step (g_lds exchange); no other intra-step sync.

#define S_LEN 512
#define BATCH 128
#define ISZ   256
#define HSZ   512

typedef __attribute__((ext_vector_type(8))) short    s16x8;
typedef __attribute__((ext_vector_type(4))) float    f32x4;
typedef __attribute__((ext_vector_type(4))) unsigned u32x4;

#define HOFF    4096
#define HXSLOT  ((size_t)BATCH * HSZ)                // u32 words per slot
#define HXBYTES ((size_t)2 * BATCH * HSZ * 4)        // 512 KiB
#define XOFF    (HOFF + HXBYTES)
#define XBYTES  ((size_t)S_LEN * BATCH * ISZ * 2)    // 32 MiB
#define WS_NEED (XOFF + XBYTES)

__device__ __forceinline__ unsigned short f2bf(float f) {
    unsigned u = __float_as_uint(f);
    u += 0x7fffu + ((u >> 16) & 1u);                 // RNE
    return (unsigned short)(u >> 16);
}

__device__ __forceinline__ s16x8 ld8f_bf(const float* p) {
    f32x4 a = *(const f32x4*)p;
    f32x4 b = *(const f32x4*)(p + 4);
    s16x8 r;
    r[0] = (short)f2bf(a[0]); r[1] = (short)f2bf(a[1]);
    r[2] = (short)f2bf(a[2]); r[3] = (short)f2bf(a[3]);
    r[4] = (short)f2bf(b[0]); r[5] = (short)f2bf(b[1]);
    r[6] = (short)f2bf(b[2]); r[7] = (short)f2bf(b[3]);
    return r;
}

__device__ __forceinline__ s16x8 pack8(u32x4 a, u32x4 b) {   // low16 of 8 u32 -> bf16x8
    s16x8 r;
    r[0] = (short)a[0]; r[1] = (short)a[1]; r[2] = (short)a[2]; r[3] = (short)a[3];
    r[4] = (short)b[0]; r[5] = (short)b[1]; r[6] = (short)b[2]; r[7] = (short)b[3];
    return r;
}

__global__ void __launch_bounds__(256, 1)
cvt_x_kernel(const float* __restrict__ x, unsigned short* __restrict__ xbf, int n8) {
    int i = blockIdx.x * blockDim.x + threadIdx.x;
    const int stride = gridDim.x * blockDim.x;
    for (; i < n8; i += stride)
        *(s16x8*)(xbf + (size_t)i * 8) = ld8f_bf(x + (size_t)i * 8);
}

#define MFMA_BF16 __builtin_amdgcn_mfma_f32_16x16x32_bf16

template <bool BIGWS>
__global__ void __launch_bounds__(256, 1)
lstm_tag(const float* __restrict__ x,
         const float* __restrict__ W,
         const float* __restrict__ bW,
         const float* __restrict__ U,
         const float* __restrict__ bU,
         float* __restrict__ out,
         unsigned char* __restrict__ ws)
{
    __shared__ float g_lds[2][2][32][33];            // [parity][K-half][row][col]

    const int tid  = threadIdx.x;
    const int bid  = blockIdx.x;
    const int grp  = bid >> 6;                       // 4 groups of 32 batch rows
    const int wg   = bid & 63;
    const int jBase = wg * 8;                        // H-col base
    const int rBase = grp * 32;                      // batch-row base

    unsigned* hx = (unsigned*)(ws + HOFF);           // tagged exchange, 2 slots
    const unsigned short* xbf = (const unsigned short*)(ws + XOFF);

    // ---- wave geometry: (mq,nq) = (row-half, K-half) ----
    const int wv   = tid >> 6;
    const int lane = tid & 63;
    const int l15  = lane & 15;
    const int lq   = lane >> 4;                      // k sub-group 0..3
    const int mq   = wv >> 1, nq = wv & 1;
    const int arow = rBase + mq * 16 + l15;          // batch row of A fragments

    // ---- step-invariant B fragments (both 16-col tiles, own K-half only) ----
    s16x8 ub[2][8], wb[2][4];
    float bias[2];
    #pragma unroll
    for (int n = 0; n < 2; ++n) {
        const int c = n * 16 + l15;                  // WG-local gate-col
        const int gRow = (c >> 3) * HSZ + jBase + (c & 7);
        bias[n] = (nq == 0) ? (bW[gRow] + bU[gRow]) : 0.f;
        #pragma unroll
        for (int ki = 0; ki < 8; ++ki)
            ub[n][ki] = ld8f_bf(U + (size_t)gRow * HSZ + nq * 256 + ki * 32 + lq * 8);
        #pragma unroll
        for (int ki = 0; ki < 4; ++ki)
            wb[n][ki] = ld8f_bf(W + (size_t)gRow * ISZ + nq * 128 + ki * 32 + lq * 8);
    }

    // ---- epilogue mapping: 256 threads x 1 cell ----
    const int er   = tid >> 3;                       // local row 0..31
    const int ej   = tid & 7;                        // local H-col 0..7
    const int orow = rBase + er;
    const int ocol = jBase + ej;
    float cst = 0.f;

    for (int t = 0; t < S_LEN; ++t) {
        const int par = t & 1;
        f32x4 acc0 = { bias[0], bias[0], bias[0], bias[0] };
        f32x4 acc1 = { bias[1], bias[1], bias[1], bias[1] };

        // x @ W^T (own K-half) -- overlaps other WGs' publish tails
        #pragma unroll
        for (int ki = 0; ki < 4; ++ki) {
            s16x8 a;
            if constexpr (BIGWS)
                a = *(const s16x8*)(xbf + ((size_t)t * BATCH + arow) * ISZ
                                    + nq * 128 + ki * 32 + lq * 8);
            else
                a = ld8f_bf(x + ((size_t)t * BATCH + arow) * ISZ
                            + nq * 128 + ki * 32 + lq * 8);
            acc0 = MFMA_BF16(a, wb[0][ki], acc0, 0, 0, 0);
            acc1 = MFMA_BF16(a, wb[1][ki], acc1, 0, 0, 0);
        }

        if (t > 0) {
            // ---- speculative tagged load of h_{t-1} A-fragments (own K-half) ----
            const unsigned* hp = hx + (size_t)(par ^ 1) * HXSLOT
                                 + (size_t)arow * HSZ + nq * 256 + lq * 8;
            const unsigned tagw = (unsigned)t << 16;
            u32x4 L0,L1,L2,L3,L4,L5,L6,L7,L8,L9,L10,L11,L12,L13,L14,L15;
            for (;;) {
#define LDT(d, o) asm volatile("global_load_dwordx4 %0, %1, off offset:" o " sc0 sc1" \
                               : "=v"(d) : "v"(hp) : "memory")
                LDT(L0,"0");    LDT(L1,"16");   LDT(L2,"128");  LDT(L3,"144");
                LDT(L4,"256");  LDT(L5,"272");  LDT(L6,"384");  LDT(L7,"400");
                LDT(L8,"512");  LDT(L9,"528");  LDT(L10,"640"); LDT(L11,"656");
                LDT(L12,"768"); LDT(L13,"784"); LDT(L14,"896"); LDT(L15,"912");
#undef LDT
                asm volatile("s_waitcnt vmcnt(0)" ::: "memory");
                __builtin_amdgcn_sched_barrier(0);   // keep tag check below the wait
                unsigned bad = 0;
#define CHK(L) { bad |= (L[0] ^ tagw) & 0xFFFF0000u; bad |= (L[1] ^ tagw) & 0xFFFF0000u; \
                 bad |= (L[2] ^ tagw) & 0xFFFF0000u; bad |= (L[3] ^ tagw) & 0xFFFF0000u; }
                CHK(L0)  CHK(L1)  CHK(L2)  CHK(L3)  CHK(L4)  CHK(L5)  CHK(L6)  CHK(L7)
                CHK(L8)  CHK(L9)  CHK(L10) CHK(L11) CHK(L12) CHK(L13) CHK(L14) CHK(L15)
#undef CHK
                if (__all(bad == 0)) break;
                __builtin_amdgcn_s_sleep(1);
            }

            s16x8 a;
            a = pack8(L0,  L1);  acc0 = MFMA_BF16(a, ub[0][0], acc0, 0, 0, 0);
                                 acc1 = MFMA_BF16(a, ub[1][0], acc1, 0, 0, 0);
            a = pack8(L2,  L3);  acc0 = MFMA_BF16(a, ub[0][1], acc0, 0, 0, 0);
                                 acc1 = MFMA_BF16(a, ub[1][1], acc1, 0, 0, 0);
            a = pack8(L4,  L5);  acc0 = MFMA_BF16(a, ub[0][2], acc0, 0, 0, 0);
                                 acc1 = MFMA_BF16(a, ub[1][2], acc1, 0, 0, 0);
            a = pack8(L6,  L7);  acc0 = MFMA_BF16(a, ub[0][3], acc0, 0, 0, 0);
                                 acc1 = MFMA_BF16(a, ub[1][3], acc1, 0, 0, 0);
            a = pack8(L8,  L9);  acc0 = MFMA_BF16(a, ub[0][4], acc0, 0, 0, 0);
                                 acc1 = MFMA_BF16(a, ub[1][4], acc1, 0, 0, 0);
            a = pack8(L10, L11); acc0 = MFMA_BF16(a, ub[0][5], acc0, 0, 0, 0);
                                 acc1 = MFMA_BF16(a, ub[1][5], acc1, 0, 0, 0);
            a = pack8(L12, L13); acc0 = MFMA_BF16(a, ub[0][6], acc0, 0, 0, 0);
                                 acc1 = MFMA_BF16(a, ub[1][6], acc1, 0, 0, 0);
            a = pack8(L14, L15); acc0 = MFMA_BF16(a, ub[0][7], acc0, 0, 0, 0);
                                 acc1 = MFMA_BF16(a, ub[1][7], acc1, 0, 0, 0);
        }

        // ---- write K-half partials to this parity's plane ----
        #pragma unroll
        for (int r = 0; r < 4; ++r) {
            g_lds[par][nq][mq * 16 + lq * 4 + r][l15]      = acc0[r];
            g_lds[par][nq][mq * 16 + lq * 4 + r][16 + l15] = acc1[r];
        }
        __syncthreads();                              // the ONLY intra-step sync

        // ---- epilogue: all 256 threads, one cell each ----
        const float gf = g_lds[par][0][er][ej]      + g_lds[par][1][er][ej];
        const float gi = g_lds[par][0][er][8 + ej]  + g_lds[par][1][er][8 + ej];
        const float go = g_lds[par][0][er][16 + ej] + g_lds[par][1][er][16 + ej];
        const float gc = g_lds[par][0][er][24 + ej] + g_lds[par][1][er][24 + ej];

        const float fg = 1.f / (1.f + __expf(-gf));
        const float ig = 1.f / (1.f + __expf(-gi));
        const float og = 1.f / (1.f + __expf(-go));
        const float ec = __expf(-2.f * fabsf(gc));
        const float cd = copysignf((1.f - ec) / (1.f + ec), gc);
        cst = fg * cst + ig * cd;
        const float eh = __expf(-2.f * fabsf(cst));
        const float hn = og * copysignf((1.f - eh) / (1.f + eh), cst);

        if (t < S_LEN - 1) {
            // publish tagged h_t: fire-and-forget (no ack, no flag).
            // WW-ordering vs step t-2's store to the same address is guaranteed
            // by the vmcnt(0) inside step t-1's/t's poll.
            unsigned wv_ = ((unsigned)(t + 1) << 16) | (unsigned)f2bf(hn);
            unsigned* hd = hx + (size_t)par * HXSLOT + (size_t)orow * HSZ + ocol;
            asm volatile("global_store_dword %0, %1, off sc0 sc1"
                         :: "v"(hd), "v"(wv_) : "memory");
            out[((size_t)t * BATCH + orow) * HSZ + ocol] = hn;   // h_seq, off-path
        } else {
            out[((size_t)t * BATCH + orow) * HSZ + ocol] = hn;
            const size_t HSEQ = (size_t)S_LEN * BATCH * HSZ;
            out[HSEQ + (size_t)orow * HSZ + ocol] = hn;          // h_final
            out[HSEQ + (size_t)BATCH * HSZ + (size_t)orow * HSZ + ocol] = cst; // c_final
        }
    }
}

extern "C" void kernel_launch(void* const* d_in, const int* in_sizes, int n_in,
                              void* d_out, int out_size, void* d_ws, size_t ws_size,
                              hipStream_t stream) {
    const float* x  = (const float*)d_in[0];
    const float* W  = (const float*)d_in[1];
    const float* bW = (const float*)d_in[2];
    const float* U  = (const float*)d_in[3];
    const float* bU = (const float*)d_in[4];
    float* out = (float*)d_out;
    unsigned char* ws = (unsigned char*)d_ws;

    // zero the tagged-exchange region every launch (tags must start != 1..511;
    // ws is NOT re-poisoned between graph replays)
    hipMemsetAsync(ws, 0, HOFF + HXBYTES, stream);

    void* args[] = { (void*)&x, (void*)&W, (void*)&bW, (void*)&U, (void*)&bU,
                     (void*)&out, (void*)&ws };

    if (ws_size >= WS_NEED) {
        const int n8 = S_LEN * BATCH * ISZ / 8;
        cvt_x_kernel<<<2048, 256, 0, stream>>>(x, (unsigned short*)(ws + XOFF), n8);
        hipError_t e = hipLaunchCooperativeKernel((void*)lstm_tag<true>, dim3(256),
                                                  dim3(256), args, 0, stream);
        if (e != hipSuccess)
            lstm_tag<true><<<dim3(256), dim3(256), 0, stream>>>(x, W, bW, U, bU, out, ws);
    } else {
        hipError_t e = hipLaunchCooperativeKernel((void*)lstm_tag<false>, dim3(256),
                                                  dim3(256), args, 0, stream);
        if (e != hipSuccess)
            lstm_tag<false><<<dim3(256), dim3(256), 0, stream>>>(x, W, bW, U, bU, out, ws);
    }
}

// Round 10
// 1322.672 us; speedup vs baseline: 1.6086x; 1.6086x over previous
//
#include <hip/hip_runtime.h>
#include <hip/hip_bf16.h>

// LSTM: S=512, B=128, I=256, H=512. Gates stacked (f,i,o,c) along dim0 of W/U.
// FP32 tensors; MFMA in bf16; epilogue/state fp32.
//
// Persistent cooperative kernel, 256 WGs x 256 thr, ALL exchange sc0 sc1 (IF$):
//   - 8 groups x 16 batch rows (grp = bid&7, static); 32 WGs/group x 16 H-cols.
//   - Waves = 4 K-QUARTERS: each wave loads a disjoint 16x128 h slice (4 KB)
//     and computes all 64 gate-cols of the WG over its K-quarter.
//     => 4 MB/step total h broadcast (half of round 6), zero duplication.
//   - acc[n] == gate n. Partials in 4 LDS planes (parity-double-buffered),
//     summed in a full-width epilogue; one __syncthreads per step.
//   - Per-wave flag release (h store -> vmcnt(0) -> flag), per-wave poll of
//     the 32 producer-wave flags. No atomics, no XCD logic, no detection.

#define S_LEN 512
#define BATCH 128
#define ISZ   256
#define HSZ   512

typedef __attribute__((ext_vector_type(8))) short  s16x8;
typedef __attribute__((ext_vector_type(4))) float  f32x4;

#define FLAG_BYTES 4096                              // 8 groups x 128 flags x 4B
#define HOFF   4096
#define HBYTES ((size_t)2 * BATCH * HSZ * 2)         // 256 KiB (2 parity slots)
#define XOFF   (HOFF + HBYTES)
#define XBYTES ((size_t)S_LEN * BATCH * ISZ * 2)     // 32 MiB
#define WS_NEED (XOFF + XBYTES)

__device__ __forceinline__ unsigned short f2bf(float f) {
    unsigned u = __float_as_uint(f);
    u += 0x7fffu + ((u >> 16) & 1u);                 // RNE
    return (unsigned short)(u >> 16);
}

__device__ __forceinline__ s16x8 ld8f_bf(const float* p) {
    f32x4 a = *(const f32x4*)p;
    f32x4 b = *(const f32x4*)(p + 4);
    s16x8 r;
    r[0] = (short)f2bf(a[0]); r[1] = (short)f2bf(a[1]);
    r[2] = (short)f2bf(a[2]); r[3] = (short)f2bf(a[3]);
    r[4] = (short)f2bf(b[0]); r[5] = (short)f2bf(b[1]);
    r[6] = (short)f2bf(b[2]); r[7] = (short)f2bf(b[3]);
    return r;
}

__global__ void __launch_bounds__(256, 1)
cvt_x_kernel(const float* __restrict__ x, unsigned short* __restrict__ xbf, int n8) {
    int i = blockIdx.x * blockDim.x + threadIdx.x;
    const int stride = gridDim.x * blockDim.x;
    for (; i < n8; i += stride)
        *(s16x8*)(xbf + (size_t)i * 8) = ld8f_bf(x + (size_t)i * 8);
}

#define MFMA_BF16 __builtin_amdgcn_mfma_f32_16x16x32_bf16

template <bool BIGWS>
__global__ void __launch_bounds__(256, 1)
lstm_kq(const float* __restrict__ x,
        const float* __restrict__ W,
        const float* __restrict__ bW,
        const float* __restrict__ U,
        const float* __restrict__ bU,
        float* __restrict__ out,
        unsigned char* __restrict__ ws)
{
    __shared__ float g_lds[2][4][16][68];            // [parity][K-quarter][row][gcol]

    const int tid  = threadIdx.x;
    const int bid  = blockIdx.x;
    const int grp  = bid & 7;                        // 8 groups of 16 batch rows
    const int wg   = bid >> 3;                       // 32 WGs per group
    const int jBase = wg * 16;                       // H-col base
    const int rBase = grp * 16;                      // batch-row base

    unsigned* flags = (unsigned*)ws;                 // [grp][wg][wave]
    unsigned short* h0 = (unsigned short*)(ws + HOFF);
    unsigned short* h1 = h0 + BATCH * HSZ;
    const unsigned short* xbf = (const unsigned short*)(ws + XOFF);

    // ---- wave geometry: wv = K-quarter ----
    const int kq   = tid >> 6;
    const int lane = tid & 63;
    const int l15  = lane & 15;
    const int lq   = lane >> 4;                      // k sub-group 0..3
    const int arow = rBase + l15;                    // batch row of A fragments

    // ---- step-invariant B fragments: 4 gate-tiles x own K-quarter ----
    // WG-local gate-col c = n*16 + l15  =>  gate n, H-col jBase + l15.
    s16x8 ub[4][4], wb[4][2];
    float bias[4];
    #pragma unroll
    for (int n = 0; n < 4; ++n) {
        const int gRow = n * HSZ + jBase + l15;
        bias[n] = (kq == 0) ? (bW[gRow] + bU[gRow]) : 0.f;
        #pragma unroll
        for (int ki = 0; ki < 4; ++ki)
            ub[n][ki] = ld8f_bf(U + (size_t)gRow * HSZ + kq * 128 + ki * 32 + lq * 8);
        #pragma unroll
        for (int ki = 0; ki < 2; ++ki)
            wb[n][ki] = ld8f_bf(W + (size_t)gRow * ISZ + kq * 64 + ki * 32 + lq * 8);
    }

    // ---- epilogue mapping: 256 threads x 1 cell (16 rows x 16 H-cols) ----
    const int er = tid >> 4, ej = tid & 15;
    const int orow = rBase + er, ocol = jBase + ej;
    float cst = 0.f;

    for (int t = 0; t < S_LEN; ++t) {
        const int par = t & 1;
        f32x4 acc[4] = { { bias[0], bias[0], bias[0], bias[0] },
                         { bias[1], bias[1], bias[1], bias[1] },
                         { bias[2], bias[2], bias[2], bias[2] },
                         { bias[3], bias[3], bias[3], bias[3] } };

        // x @ W^T (own K-quarter of I=256) -- overlaps other WGs' release tails
        #pragma unroll
        for (int ki = 0; ki < 2; ++ki) {
            s16x8 a;
            if constexpr (BIGWS)
                a = *(const s16x8*)(xbf + ((size_t)t * BATCH + arow) * ISZ
                                    + kq * 64 + ki * 32 + lq * 8);
            else
                a = ld8f_bf(x + ((size_t)t * BATCH + arow) * ISZ
                            + kq * 64 + ki * 32 + lq * 8);
            #pragma unroll
            for (int n = 0; n < 4; ++n)
                acc[n] = MFMA_BF16(a, wb[n][ki], acc[n], 0, 0, 0);
        }

        if (t > 0) {
            // ---- per-wave poll: producers of h cols [kq*128, kq*128+128)
            //      = WGs [kq*8, kq*8+8), waves 0..3 -> flags [kq*32, kq*32+32)
            const unsigned* fp = flags + grp * 128 + kq * 32 + (lane & 31);
            const unsigned tgt = (unsigned)t;
            for (;;) {
                unsigned v;
                asm volatile("global_load_dword %0, %1, off sc0 sc1\n\t"
                             "s_waitcnt vmcnt(0)" : "=v"(v) : "v"(fp) : "memory");
                if (__all(v >= tgt)) break;
            }
            __builtin_amdgcn_sched_barrier(0);

            // ---- h_{t-1} A-fragments: own disjoint 16x128 slice (4 loads) ----
            const unsigned short* hp = (par ? h0 : h1)
                                       + (size_t)arow * HSZ + kq * 128 + lq * 8;
            s16x8 f0, f1, f2, f3;
#define LDH(d, o) asm volatile("global_load_dwordx4 %0, %1, off offset:" o " sc0 sc1" \
                               : "=v"(d) : "v"(hp) : "memory")
            LDH(f0, "0"); LDH(f1, "64"); LDH(f2, "128"); LDH(f3, "192");
#undef LDH
            asm volatile("s_waitcnt vmcnt(2)" ::: "memory");
            __builtin_amdgcn_sched_barrier(0);
            #pragma unroll
            for (int n = 0; n < 4; ++n)
                acc[n] = MFMA_BF16(f0, ub[n][0], acc[n], 0, 0, 0);
            #pragma unroll
            for (int n = 0; n < 4; ++n)
                acc[n] = MFMA_BF16(f1, ub[n][1], acc[n], 0, 0, 0);
            asm volatile("s_waitcnt vmcnt(0)" ::: "memory");
            __builtin_amdgcn_sched_barrier(0);
            #pragma unroll
            for (int n = 0; n < 4; ++n)
                acc[n] = MFMA_BF16(f2, ub[n][2], acc[n], 0, 0, 0);
            #pragma unroll
            for (int n = 0; n < 4; ++n)
                acc[n] = MFMA_BF16(f3, ub[n][3], acc[n], 0, 0, 0);
        }

        // ---- write K-quarter partials to own plane ----
        #pragma unroll
        for (int n = 0; n < 4; ++n)
            #pragma unroll
            for (int r = 0; r < 4; ++r)
                g_lds[par][kq][lq * 4 + r][n * 16 + l15] = acc[n][r];
        __syncthreads();                              // the ONLY intra-step sync

        // ---- epilogue: all 256 threads, one cell each; sum 4 K-planes ----
        const float gf = g_lds[par][0][er][ej]      + g_lds[par][1][er][ej]
                       + g_lds[par][2][er][ej]      + g_lds[par][3][er][ej];
        const float gi = g_lds[par][0][er][16 + ej] + g_lds[par][1][er][16 + ej]
                       + g_lds[par][2][er][16 + ej] + g_lds[par][3][er][16 + ej];
        const float go = g_lds[par][0][er][32 + ej] + g_lds[par][1][er][32 + ej]
                       + g_lds[par][2][er][32 + ej] + g_lds[par][3][er][32 + ej];
        const float gc = g_lds[par][0][er][48 + ej] + g_lds[par][1][er][48 + ej]
                       + g_lds[par][2][er][48 + ej] + g_lds[par][3][er][48 + ej];

        const float fg = 1.f / (1.f + __expf(-gf));
        const float ig = 1.f / (1.f + __expf(-gi));
        const float og = 1.f / (1.f + __expf(-go));
        const float ec = __expf(-2.f * fabsf(gc));
        const float cd = copysignf((1.f - ec) / (1.f + ec), gc);
        cst = fg * cst + ig * cd;
        const float eh = __expf(-2.f * fabsf(cst));
        const float hn = og * copysignf((1.f - eh) / (1.f + eh), cst);

        if (t < S_LEN - 1) {
            // publish h_t -> IF$, ack own wave's stores, then per-wave flag
            unsigned hv = (unsigned)f2bf(hn);
            unsigned short* hd = (par ? h1 : h0) + (size_t)orow * HSZ + ocol;
            asm volatile("global_store_short %0, %1, off sc0 sc1"
                         :: "v"(hd), "v"(hv) : "memory");
            asm volatile("s_waitcnt vmcnt(0)" ::: "memory");
            if (lane == 0) {
                unsigned* fl = flags + grp * 128 + wg * 4 + kq;
                unsigned ep = (unsigned)(t + 1);
                asm volatile("global_store_dword %0, %1, off sc0 sc1"
                             :: "v"(fl), "v"(ep) : "memory");
            }
            out[((size_t)t * BATCH + orow) * HSZ + ocol] = hn;   // h_seq, off-path
        } else {
            out[((size_t)t * BATCH + orow) * HSZ + ocol] = hn;
            const size_t HSEQ = (size_t)S_LEN * BATCH * HSZ;
            out[HSEQ + (size_t)orow * HSZ + ocol] = hn;          // h_final
            out[HSEQ + (size_t)BATCH * HSZ + (size_t)orow * HSZ + ocol] = cst; // c_final
        }
    }
}

extern "C" void kernel_launch(void* const* d_in, const int* in_sizes, int n_in,
                              void* d_out, int out_size, void* d_ws, size_t ws_size,
                              hipStream_t stream) {
    const float* x  = (const float*)d_in[0];
    const float* W  = (const float*)d_in[1];
    const float* bW = (const float*)d_in[2];
    const float* U  = (const float*)d_in[3];
    const float* bU = (const float*)d_in[4];
    float* out = (float*)d_out;
    unsigned char* ws = (unsigned char*)d_ws;

    // per-wave epoch flags must be 0 at every launch (ws not re-poisoned)
    hipMemsetAsync(ws, 0, FLAG_BYTES, stream);

    void* args[] = { (void*)&x, (void*)&W, (void*)&bW, (void*)&U, (void*)&bU,
                     (void*)&out, (void*)&ws };

    if (ws_size >= WS_NEED) {
        const int n8 = S_LEN * BATCH * ISZ / 8;
        cvt_x_kernel<<<2048, 256, 0, stream>>>(x, (unsigned short*)(ws + XOFF), n8);
        hipError_t e = hipLaunchCooperativeKernel((void*)lstm_kq<true>, dim3(256),
                                                  dim3(256), args, 0, stream);
        if (e != hipSuccess)
            lstm_kq<true><<<dim3(256), dim3(256), 0, stream>>>(x, W, bW, U, bU, out, ws);
    } else {
        hipError_t e = hipLaunchCooperativeKernel((void*)lstm_kq<false>, dim3(256),
                                                  dim3(256), args, 0, stream);
        if (e != hipSuccess)
            lstm_kq<false><<<dim3(256), dim3(256), 0, stream>>>(x, W, bW, U, bU, out, ws);
    }
}